// Round 11
// baseline (305.256 us; speedup 1.0000x reference)
//
#include <hip/hip_runtime.h>
#include <hip/hip_fp16.h>

#define LEAKY 0.2f
#define BSH 7
#define BN 128      // nodes per bucket = 1<<BSH
#define CHUNK 4096  // edges per partition workgroup
#define NBMAX 1024  // max buckets supported by LDS arrays

__device__ __forceinline__ float leaky(float l) {
  return l >= 0.f ? l : LEAKY * l;
}

typedef _Float16 f16x2 __attribute__((ext_vector_type(2)));

__device__ __forceinline__ float fdot2(unsigned a, unsigned b, float c) {
#if __has_builtin(__builtin_amdgcn_fdot2)
  return __builtin_amdgcn_fdot2(__builtin_bit_cast(f16x2, a),
                                __builtin_bit_cast(f16x2, b), c, false);
#else
  __half2 ha = *(__half2*)&a, hb = *(__half2*)&b;
  float2 fa = __half22float2(ha), fb = __half22float2(hb);
  return fmaf(fa.x, fb.x, fmaf(fa.y, fb.y, c));
#endif
}

__device__ __forceinline__ int packsplat(float w) {
  const __half2 s = __half2half2(__float2half(w));
  return *(const int*)&s;
}
__device__ __forceinline__ __half2 asH2(unsigned u) { return *(__half2*)&u; }

// ---------------- Tiled GEMM (fp16 LDS operands, dot2 inner, fp16-only output) ----------------
template<int K, int CO, int H, bool IN_F32>
__global__ __launch_bounds__(256, 6)
void gat_gemm3(const void* __restrict__ xin, const float* __restrict__ W,
               const float* __restrict__ atts, const float* __restrict__ attd,
               __half* __restrict__ hh, float* __restrict__ sa, float* __restrict__ da,
               int N) {
  constexpr int CG = CO / 4;          // 16 or 8
  constexpr int BM = (256 / CG) * 4;  // 64 or 128
  constexpr int BK = 64;
  constexpr int NK = K / BK;
  constexpr int C = CO / H;
  constexpr int LDW = BK / 2 + 4;

  __shared__ unsigned xs[BM][LDW];
  __shared__ unsigned ws[CO][LDW];

  const int t = (int)threadIdx.x;
  const int cg = t % CG;
  const int ng = t / CG;
  const int n0 = (int)blockIdx.x * BM;

  float acc[4][4] = {};

  for (int kb = 0; kb < NK; ++kb) {
    __syncthreads();
    if constexpr (IN_F32) {
      const float* x = (const float*)xin;
      constexpr int F4R = BK / 4;
      constexpr int TOT = BM * F4R;
      for (int f = t; f < TOT; f += 256) {
        const int r = f / F4R, c = f % F4R;
        int row = n0 + r; row = row < N ? row : N - 1;
        const float4 v = *(const float4*)(x + (size_t)row * K + kb * BK + c * 4);
        const __half2 h0 = __floats2half2_rn(v.x, v.y);
        const __half2 h1 = __floats2half2_rn(v.z, v.w);
        xs[r][c * 2]     = *(const unsigned*)&h0;
        xs[r][c * 2 + 1] = *(const unsigned*)&h1;
      }
    } else {
      const __half* x = (const __half*)xin;
      constexpr int U4R = BK / 8;
      constexpr int TOT = BM * U4R;
      for (int f = t; f < TOT; f += 256) {
        const int r = f / U4R, c = f % U4R;
        int row = n0 + r; row = row < N ? row : N - 1;
        const uint4 v = *(const uint4*)(x + (size_t)row * K + kb * BK + c * 8);
        *(uint4*)&xs[r][c * 4] = v;
      }
    }
    {
      constexpr int F4R = BK / 4;
      constexpr int TOT = CO * F4R;
      for (int f = t; f < TOT; f += 256) {
        const int r = f / F4R, c = f % F4R;
        const float4 v = *(const float4*)(W + (size_t)r * K + kb * BK + c * 4);
        const __half2 h0 = __floats2half2_rn(v.x, v.y);
        const __half2 h1 = __floats2half2_rn(v.z, v.w);
        ws[r][c * 2]     = *(const unsigned*)&h0;
        ws[r][c * 2 + 1] = *(const unsigned*)&h1;
      }
    }
    __syncthreads();
    #pragma unroll
    for (int k = 0; k < BK; k += 8) {
      uint4 xa[4], wb[4];
      #pragma unroll
      for (int i = 0; i < 4; ++i) xa[i] = *(const uint4*)&xs[ng * 4 + i][k / 2];
      #pragma unroll
      for (int j = 0; j < 4; ++j) wb[j] = *(const uint4*)&ws[cg + CG * j][k / 2];
      #pragma unroll
      for (int i = 0; i < 4; ++i) {
        #pragma unroll
        for (int j = 0; j < 4; ++j) {
          acc[i][j] = fdot2(xa[i].x, wb[j].x, acc[i][j]);
          acc[i][j] = fdot2(xa[i].y, wb[j].y, acc[i][j]);
          acc[i][j] = fdot2(xa[i].z, wb[j].z, acc[i][j]);
          acc[i][j] = fdot2(xa[i].w, wb[j].w, acc[i][j]);
        }
      }
    }
  }

  float as_[4], ad_[4];
  #pragma unroll
  for (int j = 0; j < 4; ++j) {
    as_[j] = atts[cg + CG * j];
    ad_[j] = attd[cg + CG * j];
  }
  float ps[4][H] = {}, pd[4][H] = {};
  #pragma unroll
  for (int i = 0; i < 4; ++i) {
    #pragma unroll
    for (int j = 0; j < 4; ++j) {
      const int hd = (CG * j) / C;
      ps[i][hd] = fmaf(acc[i][j], as_[j], ps[i][hd]);
      pd[i][hd] = fmaf(acc[i][j], ad_[j], pd[i][hd]);
    }
  }
  #pragma unroll
  for (int m = 1; m < CG; m <<= 1) {
    #pragma unroll
    for (int i = 0; i < 4; ++i) {
      #pragma unroll
      for (int hd = 0; hd < H; ++hd) {
        ps[i][hd] += __shfl_xor(ps[i][hd], m, 64);
        pd[i][hd] += __shfl_xor(pd[i][hd], m, 64);
      }
    }
  }

  #pragma unroll
  for (int i = 0; i < 4; ++i) {
    const int n = n0 + ng * 4 + i;
    if (n < N) {
      #pragma unroll
      for (int j = 0; j < 4; ++j)
        hh[(size_t)n * CO + cg + CG * j] = __float2half(acc[i][j]);
      if (cg == 0) {
        #pragma unroll
        for (int hd = 0; hd < H; ++hd) {
          sa[n * H + hd] = ps[i][hd];
          da[n * H + hd] = pd[i][hd];
        }
      }
    }
  }
}

// ---------------- Edge aggregation, H=2 (64 ch): 4 nodes/wave, pipelined ----------------
// Lane owns 4 channels (8 B). Next block's col+sa prefetched into registers
// before the inner loop; inner loop keeps 8 gathers in flight.
__global__ __launch_bounds__(256)
void gat_edge2(const __half* __restrict__ hh,
               const float* __restrict__ sa, const float* __restrict__ da,
               const int* __restrict__ rowp, const int* __restrict__ col,
               const float* __restrict__ bias, const float* __restrict__ gamma,
               const float* __restrict__ beta, __half* __restrict__ out, int N) {
  __shared__ int2 wst[4][4][17][2];   // [wave][quarter][edge(16)+pad][head]
  const int t = (int)threadIdx.x;
  const int lane = t & 63;
  const int wib = t >> 6;
  const int quarter = lane >> 4;
  const int l = lane & 15;            // channels 4l .. 4l+3
  const int headq = l >> 3;
  const int wgl = (int)((blockIdx.x * blockDim.x + t) >> 6);
  const int n = wgl * 4 + quarter;
  const bool valid = (n < N);
  const int nc = valid ? n : N - 1;
  const int beg = rowp[nc];
  const int end = rowp[nc + 1];
  const float2 dvv = *(const float2*)(da + (size_t)nc * 2);
  const __half2* __restrict__ hhp = (const __half2*)hh;

  const __half2 z = __float2half2_rn(0.f);
  __half2 aL0 = z, aH0 = z, aL1 = z, aH1 = z, aL2 = z, aH2 = z, aL3 = z, aH3 = z;
  __half2 q0 = z, q1 = z;

  // prefetch block 0
  int sP = 0; float2 pP = make_float2(0.f, 0.f);
  if (beg < end) {
    const int cnt0 = min(16, end - beg);
    if (l < cnt0) {
      sP = col[beg + l];
      pP = *(const float2*)(sa + (size_t)sP * 2);
    }
  }

  for (int b0 = beg; b0 < end; b0 += 16) {
    const int cnt = min(16, end - b0);
    if (l < cnt) {
      int2 e0; e0.x = sP; e0.y = packsplat(__expf(leaky(pP.x + dvv.x)));
      int2 e1; e1.x = sP; e1.y = packsplat(__expf(leaky(pP.y + dvv.y)));
      wst[wib][quarter][l][0] = e0;
      wst[wib][quarter][l][1] = e1;
    }
    // prefetch next block (lands under the inner loop)
    const int nb0 = b0 + 16;
    if (nb0 < end) {
      const int ncnt = min(16, end - nb0);
      if (l < ncnt) {
        sP = col[nb0 + l];
        pP = *(const float2*)(sa + (size_t)sP * 2);
      }
    }
    int i = 0;
    for (; i + 8 <= cnt; i += 8) {
      int2 e[8];
      #pragma unroll
      for (int j = 0; j < 8; ++j) e[j] = wst[wib][quarter][i + j][headq];
      uint2 hv[8];
      #pragma unroll
      for (int j = 0; j < 8; ++j) hv[j] = *(const uint2*)(hhp + ((size_t)e[j].x << 5) + 2 * l);
      __half2 w[8];
      #pragma unroll
      for (int j = 0; j < 8; ++j) w[j] = asH2(e[j].y);
      q0 = __hadd2(q0, __hadd2(__hadd2(w[0], w[1]), __hadd2(w[2], w[3])));
      q1 = __hadd2(q1, __hadd2(__hadd2(w[4], w[5]), __hadd2(w[6], w[7])));
      aL0 = __hfma2(w[0], asH2(hv[0].x), aL0); aH0 = __hfma2(w[0], asH2(hv[0].y), aH0);
      aL1 = __hfma2(w[1], asH2(hv[1].x), aL1); aH1 = __hfma2(w[1], asH2(hv[1].y), aH1);
      aL2 = __hfma2(w[2], asH2(hv[2].x), aL2); aH2 = __hfma2(w[2], asH2(hv[2].y), aH2);
      aL3 = __hfma2(w[3], asH2(hv[3].x), aL3); aH3 = __hfma2(w[3], asH2(hv[3].y), aH3);
      aL0 = __hfma2(w[4], asH2(hv[4].x), aL0); aH0 = __hfma2(w[4], asH2(hv[4].y), aH0);
      aL1 = __hfma2(w[5], asH2(hv[5].x), aL1); aH1 = __hfma2(w[5], asH2(hv[5].y), aH1);
      aL2 = __hfma2(w[6], asH2(hv[6].x), aL2); aH2 = __hfma2(w[6], asH2(hv[6].y), aH2);
      aL3 = __hfma2(w[7], asH2(hv[7].x), aL3); aH3 = __hfma2(w[7], asH2(hv[7].y), aH3);
    }
    for (; i + 4 <= cnt; i += 4) {
      int2 e[4];
      #pragma unroll
      for (int j = 0; j < 4; ++j) e[j] = wst[wib][quarter][i + j][headq];
      uint2 hv[4];
      #pragma unroll
      for (int j = 0; j < 4; ++j) hv[j] = *(const uint2*)(hhp + ((size_t)e[j].x << 5) + 2 * l);
      __half2 w[4];
      #pragma unroll
      for (int j = 0; j < 4; ++j) w[j] = asH2(e[j].y);
      q0 = __hadd2(q0, __hadd2(__hadd2(w[0], w[1]), __hadd2(w[2], w[3])));
      aL0 = __hfma2(w[0], asH2(hv[0].x), aL0); aH0 = __hfma2(w[0], asH2(hv[0].y), aH0);
      aL1 = __hfma2(w[1], asH2(hv[1].x), aL1); aH1 = __hfma2(w[1], asH2(hv[1].y), aH1);
      aL2 = __hfma2(w[2], asH2(hv[2].x), aL2); aH2 = __hfma2(w[2], asH2(hv[2].y), aH2);
      aL3 = __hfma2(w[3], asH2(hv[3].x), aL3); aH3 = __hfma2(w[3], asH2(hv[3].y), aH3);
    }
    for (; i < cnt; ++i) {
      const int2 e = wst[wib][quarter][i][headq];
      const uint2 hv = *(const uint2*)(hhp + ((size_t)e.x << 5) + 2 * l);
      const __half2 w = asH2(e.y);
      q0 = __hadd2(q0, w);
      aL0 = __hfma2(w, asH2(hv.x), aL0);
      aH0 = __hfma2(w, asH2(hv.y), aH0);
    }
  }

  const float c0 = (__low2float(aL0) + __low2float(aL1)) + (__low2float(aL2) + __low2float(aL3));
  const float c1 = (__high2float(aL0) + __high2float(aL1)) + (__high2float(aL2) + __high2float(aL3));
  const float c2 = (__low2float(aH0) + __low2float(aH1)) + (__low2float(aH2) + __low2float(aH3));
  const float c3 = (__high2float(aH0) + __high2float(aH1)) + (__high2float(aH2) + __high2float(aH3));
  const float qf = __low2float(q0) + __low2float(q1);

  const float inv = 1.f / fmaxf(qf, 1e-16f);
  const uint2 hr = *(const uint2*)(hhp + ((size_t)nc << 5) + 2 * l);
  const float2 r01 = __half22float2(asH2(hr.x));
  const float2 r23 = __half22float2(asH2(hr.y));
  const float4 bi = *(const float4*)(bias + 4 * l);
  float v0 = c0 * inv + r01.x + bi.x;
  float v1 = c1 * inv + r01.y + bi.y;
  float v2 = c2 * inv + r23.x + bi.z;
  float v3 = c3 * inv + r23.y + bi.w;
  {
    float s = (v0 + v1) + (v2 + v3);
    #pragma unroll
    for (int m = 1; m < 16; m <<= 1) s += __shfl_xor(s, m, 64);
    const float mu = s * (1.f / 64.f);
    const float d0 = v0 - mu, d1 = v1 - mu, d2 = v2 - mu, d3 = v3 - mu;
    float vs = (d0 * d0 + d1 * d1) + (d2 * d2 + d3 * d3);
    #pragma unroll
    for (int m = 1; m < 16; m <<= 1) vs += __shfl_xor(vs, m, 64);
    const float rs = rsqrtf(vs * (1.f / 64.f) + 1e-5f);
    const float4 g = *(const float4*)(gamma + 4 * l);
    const float4 be = *(const float4*)(beta + 4 * l);
    v0 = fmaxf(d0 * rs * g.x + be.x, 0.f);
    v1 = fmaxf(d1 * rs * g.y + be.y, 0.f);
    v2 = fmaxf(d2 * rs * g.z + be.z, 0.f);
    v3 = fmaxf(d3 * rs * g.w + be.w, 0.f);
  }
  if (valid) {
    const __half2 o01 = __floats2half2_rn(v0, v1);
    const __half2 o23 = __floats2half2_rn(v2, v3);
    uint2 o; o.x = *(const unsigned*)&o01; o.y = *(const unsigned*)&o23;
    *(uint2*)(out + (size_t)n * 64 + 4 * l) = o;
  }
}

// ---------------- Edge aggregation, H=1 (32 ch): 8 nodes/wave, pipelined ----------------
__global__ __launch_bounds__(256)
void gat_edge1(const __half* __restrict__ hh,
               const float* __restrict__ sa, const float* __restrict__ da,
               const int* __restrict__ rowp, const int* __restrict__ col,
               const float* __restrict__ bias, float* __restrict__ out, int N) {
  __shared__ int2 wst[4][8][9];       // [wave][octet][edge(8)+pad]
  const int t = (int)threadIdx.x;
  const int lane = t & 63;
  const int wib = t >> 6;
  const int oct = lane >> 3;
  const int l = lane & 7;             // channels 4l .. 4l+3
  const int wgl = (int)((blockIdx.x * blockDim.x + t) >> 6);
  const int n = wgl * 8 + oct;
  const bool valid = (n < N);
  const int nc = valid ? n : N - 1;
  const int beg = rowp[nc];
  const int end = rowp[nc + 1];
  const float dv = da[nc];
  const __half2* __restrict__ hhp = (const __half2*)hh;

  const __half2 z = __float2half2_rn(0.f);
  __half2 aL0 = z, aH0 = z, aL1 = z, aH1 = z, aL2 = z, aH2 = z, aL3 = z, aH3 = z;
  __half2 q0 = z, q1 = z;

  // prefetch block 0 (8 edges per block; l spans 0..7)
  int sP = 0; float pP = 0.f;
  if (beg < end) {
    const int cnt0 = min(8, end - beg);
    if (l < cnt0) { sP = col[beg + l]; pP = sa[sP]; }
  }

  for (int b0 = beg; b0 < end; b0 += 8) {
    const int cnt = min(8, end - b0);
    if (l < cnt) {
      int2 e; e.x = sP; e.y = packsplat(__expf(leaky(pP + dv)));
      wst[wib][oct][l] = e;
    }
    const int nb0 = b0 + 8;
    if (nb0 < end) {
      const int ncnt = min(8, end - nb0);
      if (l < ncnt) { sP = col[nb0 + l]; pP = sa[sP]; }
    }
    int i = 0;
    for (; i + 8 <= cnt; i += 8) {
      int2 e[8];
      #pragma unroll
      for (int j = 0; j < 8; ++j) e[j] = wst[wib][oct][i + j];
      uint2 hv[8];
      #pragma unroll
      for (int j = 0; j < 8; ++j) hv[j] = *(const uint2*)(hhp + ((size_t)e[j].x << 4) + 2 * l);
      __half2 w[8];
      #pragma unroll
      for (int j = 0; j < 8; ++j) w[j] = asH2(e[j].y);
      q0 = __hadd2(q0, __hadd2(__hadd2(w[0], w[1]), __hadd2(w[2], w[3])));
      q1 = __hadd2(q1, __hadd2(__hadd2(w[4], w[5]), __hadd2(w[6], w[7])));
      aL0 = __hfma2(w[0], asH2(hv[0].x), aL0); aH0 = __hfma2(w[0], asH2(hv[0].y), aH0);
      aL1 = __hfma2(w[1], asH2(hv[1].x), aL1); aH1 = __hfma2(w[1], asH2(hv[1].y), aH1);
      aL2 = __hfma2(w[2], asH2(hv[2].x), aL2); aH2 = __hfma2(w[2], asH2(hv[2].y), aH2);
      aL3 = __hfma2(w[3], asH2(hv[3].x), aL3); aH3 = __hfma2(w[3], asH2(hv[3].y), aH3);
      aL0 = __hfma2(w[4], asH2(hv[4].x), aL0); aH0 = __hfma2(w[4], asH2(hv[4].y), aH0);
      aL1 = __hfma2(w[5], asH2(hv[5].x), aL1); aH1 = __hfma2(w[5], asH2(hv[5].y), aH1);
      aL2 = __hfma2(w[6], asH2(hv[6].x), aL2); aH2 = __hfma2(w[6], asH2(hv[6].y), aH2);
      aL3 = __hfma2(w[7], asH2(hv[7].x), aL3); aH3 = __hfma2(w[7], asH2(hv[7].y), aH3);
    }
    for (; i + 4 <= cnt; i += 4) {
      int2 e[4];
      #pragma unroll
      for (int j = 0; j < 4; ++j) e[j] = wst[wib][oct][i + j];
      uint2 hv[4];
      #pragma unroll
      for (int j = 0; j < 4; ++j) hv[j] = *(const uint2*)(hhp + ((size_t)e[j].x << 4) + 2 * l);
      __half2 w[4];
      #pragma unroll
      for (int j = 0; j < 4; ++j) w[j] = asH2(e[j].y);
      q0 = __hadd2(q0, __hadd2(__hadd2(w[0], w[1]), __hadd2(w[2], w[3])));
      aL0 = __hfma2(w[0], asH2(hv[0].x), aL0); aH0 = __hfma2(w[0], asH2(hv[0].y), aH0);
      aL1 = __hfma2(w[1], asH2(hv[1].x), aL1); aH1 = __hfma2(w[1], asH2(hv[1].y), aH1);
      aL2 = __hfma2(w[2], asH2(hv[2].x), aL2); aH2 = __hfma2(w[2], asH2(hv[2].y), aH2);
      aL3 = __hfma2(w[3], asH2(hv[3].x), aL3); aH3 = __hfma2(w[3], asH2(hv[3].y), aH3);
    }
    for (; i < cnt; ++i) {
      const int2 e = wst[wib][oct][i];
      const uint2 hv = *(const uint2*)(hhp + ((size_t)e.x << 4) + 2 * l);
      const __half2 w = asH2(e.y);
      q0 = __hadd2(q0, w);
      aL0 = __hfma2(w, asH2(hv.x), aL0);
      aH0 = __hfma2(w, asH2(hv.y), aH0);
    }
  }

  const float c0 = (__low2float(aL0) + __low2float(aL1)) + (__low2float(aL2) + __low2float(aL3));
  const float c1 = (__high2float(aL0) + __high2float(aL1)) + (__high2float(aL2) + __high2float(aL3));
  const float c2 = (__low2float(aH0) + __low2float(aH1)) + (__low2float(aH2) + __low2float(aH3));
  const float c3 = (__high2float(aH0) + __high2float(aH1)) + (__high2float(aH2) + __high2float(aH3));
  const float qf = __low2float(q0) + __low2float(q1);

  if (valid) {
    const float inv = 1.f / fmaxf(qf, 1e-16f);
    const uint2 hr = *(const uint2*)(hhp + ((size_t)nc << 4) + 2 * l);
    const float2 r01 = __half22float2(asH2(hr.x));
    const float2 r23 = __half22float2(asH2(hr.y));
    const float4 bi = *(const float4*)(bias + 4 * l);
    float4 o;
    o.x = c0 * inv + r01.x + bi.x;
    o.y = c1 * inv + r01.y + bi.y;
    o.z = c2 * inv + r23.x + bi.z;
    o.w = c3 * inv + r23.y + bi.w;
    *(float4*)(out + (size_t)n * 32 + 4 * l) = o;
  }
}

// ---------------- CSR build: atomic-free radix partition ----------------
// k_hist_chunk writes per-chunk histograms to cntmat[chunk*NB + b] (coalesced).
// k_colscan turns each bucket's chunk-counts into exclusive offsets + totals.
// k_part reads its reservation with two loads — zero global atomics anywhere.

__global__ __launch_bounds__(256)
void k_hist_chunk(const int* __restrict__ dst, int* __restrict__ cntmat,
                  int E, int NB) {
  __shared__ int lh[NBMAX];
  const int t = (int)threadIdx.x;
  const int chunk = (int)blockIdx.x;
  const int c0 = chunk * CHUNK;
  const int cnt = min(CHUNK, E - c0);
  for (int b = t; b < NB; b += 256) lh[b] = 0;
  __syncthreads();
  for (int i = t; i < cnt; i += 256)
    atomicAdd(&lh[dst[c0 + i] >> BSH], 1);
  __syncthreads();
  int* row = cntmat + (size_t)chunk * NB;
  for (int b = t; b < NB; b += 256) row[b] = lh[b];
}

__global__ void k_colscan(int* __restrict__ cntmat, int* __restrict__ bcnt,
                          int NB, int NW) {
  const int b = (int)(blockIdx.x * blockDim.x + threadIdx.x);
  if (b >= NB) return;
  int run = 0;
  for (int c = 0; c < NW; ++c) {
    const size_t idx = (size_t)c * NB + b;
    const int v = cntmat[idx];
    cntmat[idx] = run;
    run += v;
  }
  bcnt[b] = run;
}

__global__ void k_bscan(const int* __restrict__ bcnt, int nb,
                        int* __restrict__ bstart, int* __restrict__ rowp_last, int E) {
  __shared__ int sm[256];
  const int t = (int)threadIdx.x;
  int v[4];
  #pragma unroll
  for (int j = 0; j < 4; ++j) { int i = t * 4 + j; v[j] = (i < nb) ? bcnt[i] : 0; }
  const int tot = v[0] + v[1] + v[2] + v[3];
  sm[t] = tot; __syncthreads();
  #pragma unroll
  for (int off = 1; off < 256; off <<= 1) {
    int xv = (t >= off) ? sm[t - off] : 0;
    __syncthreads();
    sm[t] += xv;
    __syncthreads();
  }
  int excl = sm[t] - tot;
  #pragma unroll
  for (int j = 0; j < 4; ++j) {
    int i = t * 4 + j;
    if (i < nb) { bstart[i] = excl; excl += v[j]; }
  }
  if (t == 0) { bstart[nb] = E; *rowp_last = E; }
}

__global__ __launch_bounds__(256)
void k_part(const int* __restrict__ src, const int* __restrict__ dst,
            const int* __restrict__ bstart, const int* __restrict__ cntmat,
            int* __restrict__ pairs, int E, int NB) {
  __shared__ int lh[NBMAX];     // hist, then local cursor
  __shared__ int lofs[NBMAX];   // exclusive local scan
  __shared__ int gofs[NBMAX];   // reserved global run base
  __shared__ int stg[CHUNK];    // packed pairs, bucket-sorted
  __shared__ short stgb[CHUNK]; // bucket id per staged slot
  __shared__ int bsum[256];
  const int t = (int)threadIdx.x;
  const int chunk = (int)blockIdx.x;
  const int c0 = chunk * CHUNK;
  const int cnt = min(CHUNK, E - c0);

  for (int b = t; b < NB; b += 256) lh[b] = 0;
  __syncthreads();
  for (int i = t; i < cnt; i += 256)
    atomicAdd(&lh[dst[c0 + i] >> BSH], 1);
  __syncthreads();

  int v[4]; int run = 0;
  #pragma unroll
  for (int j = 0; j < 4; ++j) {
    const int b = t * 4 + j;
    v[j] = (b < NB) ? lh[b] : 0;
    run += v[j];
  }
  bsum[t] = run;
  __syncthreads();
  #pragma unroll
  for (int off = 1; off < 256; off <<= 1) {
    int xv = (t >= off) ? bsum[t - off] : 0;
    __syncthreads();
    bsum[t] += xv;
    __syncthreads();
  }
  int base = bsum[t] - run;
  #pragma unroll
  for (int j = 0; j < 4; ++j) {
    const int b = t * 4 + j;
    if (b < NB) lofs[b] = base;
    base += v[j];
  }
  __syncthreads();

  // atomic-free reservation: precomputed exclusive offsets
  const int* crow = cntmat + (size_t)chunk * NB;
  for (int b = t; b < NB; b += 256) {
    gofs[b] = bstart[b] + crow[b];
    lh[b] = lofs[b];
  }
  __syncthreads();

  for (int i = t; i < cnt; i += 256) {
    const int d = dst[c0 + i];
    const int b = d >> BSH;
    const int p = atomicAdd(&lh[b], 1);   // LDS only
    stg[p] = (src[c0 + i] << BSH) | (d & (BN - 1));
    stgb[p] = (short)b;
  }
  __syncthreads();

  for (int i = t; i < cnt; i += 256) {
    const int b = (int)stgb[i];
    pairs[gofs[b] + (i - lofs[b])] = stg[i];
  }
}

__global__ __launch_bounds__(256)
void k_bucket_csr(const int* __restrict__ pairs, const int* __restrict__ bstart,
                  int* __restrict__ rowp, int* __restrict__ col, int N) {
  __shared__ int ldeg[BN];
  __shared__ int lofs[BN];
  const int b = (int)blockIdx.x;
  const int t = (int)threadIdx.x;
  const int base = b << BSH;
  const int nn = min(BN, N - base);
  const int s0 = bstart[b];
  const int s1 = bstart[b + 1];

  if (t < BN) ldeg[t] = 0;
  __syncthreads();
  for (int i = s0 + t; i < s1; i += 256)
    atomicAdd(&ldeg[pairs[i] & (BN - 1)], 1);
  __syncthreads();
  if (t < BN) lofs[t] = ldeg[t];
  __syncthreads();
  #pragma unroll
  for (int off = 1; off < BN; off <<= 1) {
    int v = (t < BN && t >= off) ? lofs[t - off] : 0;
    __syncthreads();
    if (t < BN) lofs[t] += v;
    __syncthreads();
  }
  if (t < BN) {
    const int ofs = s0 + lofs[t] - ldeg[t];
    if (t < nn) rowp[base + t] = ofs;
    ldeg[t] = ofs;
  }
  __syncthreads();
  for (int i = s0 + t; i < s1; i += 256) {
    const int pr = pairs[i];
    const int p = atomicAdd(&ldeg[pr & (BN - 1)], 1);
    col[p] = pr >> BSH;
  }
}

extern "C" void kernel_launch(void* const* d_in, const int* in_sizes, int n_in,
                              void* d_out, int out_size, void* d_ws, size_t ws_size,
                              hipStream_t stream) {
  const float* x   = (const float*)d_in[0];
  const int* esrc  = (const int*)d_in[1];
  const int* edst  = (const int*)d_in[2];
  const float* W1  = (const float*)d_in[3];
  const float* as1 = (const float*)d_in[4];
  const float* ad1 = (const float*)d_in[5];
  const float* b1  = (const float*)d_in[6];
  const float* W2  = (const float*)d_in[7];
  const float* as2 = (const float*)d_in[8];
  const float* ad2 = (const float*)d_in[9];
  const float* b2  = (const float*)d_in[10];
  const float* W3  = (const float*)d_in[11];
  const float* as3 = (const float*)d_in[12];
  const float* ad3 = (const float*)d_in[13];
  const float* b3  = (const float*)d_in[14];
  const float* g1  = (const float*)d_in[15];
  const float* be1 = (const float*)d_in[16];
  const float* g2  = (const float*)d_in[17];
  const float* be2 = (const float*)d_in[18];

  const int N = in_sizes[0] / 128;
  const int E = in_sizes[1];
  const int NB = (N + BN - 1) / BN;
  const int NW = (E + CHUNK - 1) / CHUNK;

  char* ws = (char*)d_ws;
  size_t off = 0;
  auto alloc = [&](size_t bytes) -> void* {
    void* p = ws + off;
    off = (off + bytes + 255) & ~(size_t)255;
    return p;
  };
  __half* lnbuf = (__half*)alloc((size_t)N * 64 * 2);
  __half* hh   = (__half*)alloc((size_t)N * 64 * 2);
  float* sab   = (float*)alloc((size_t)N * 2 * 4);
  float* dab   = (float*)alloc((size_t)N * 2 * 4);
  int* rowp    = (int*)alloc((size_t)(N + 1) * 4);
  int* colb    = (int*)alloc((size_t)E * 4);
  int* bcnt    = (int*)alloc((size_t)NB * 4);
  int* bstart  = (int*)alloc((size_t)(NB + 1) * 4);
  int* cntmat  = (int*)alloc((size_t)NW * NB * 4);
  // pairs buffer: reuse d_out (N*32 floats = 12.8MB >= E*4 = 6.4MB);
  // lifetime ends before the final layer writes d_out.
  int* pairs = (E <= out_size) ? (int*)d_out : (int*)alloc((size_t)E * 4);
  (void)ws_size; (void)n_in;

  // ---- CSR build (zero global atomics) ----
  k_hist_chunk<<<NW, 256, 0, stream>>>(edst, cntmat, E, NB);
  k_colscan<<<(NB + 255) / 256, 256, 0, stream>>>(cntmat, bcnt, NB, NW);
  k_bscan<<<1, 256, 0, stream>>>(bcnt, NB, bstart, rowp + N, E);
  k_part<<<NW, 256, 0, stream>>>(esrc, edst, bstart, cntmat, pairs, E, NB);
  k_bucket_csr<<<NB, 256, 0, stream>>>(pairs, bstart, rowp, colb, N);

  const int gG12 = (N + 63) / 64;    // BM=64
  const int gG3  = (N + 127) / 128;  // BM=128
  const int gE2 = (N + 15) / 16;     // 4 nodes/wave * 4 waves/block
  const int gE1 = (N + 31) / 32;     // 8 nodes/wave * 4 waves/block

  // ---- Layer 1: 128 -> (2x32) + LN + ReLU ----
  gat_gemm3<128, 64, 2, true><<<gG12, 256, 0, stream>>>(x, W1, as1, ad1, hh, sab, dab, N);
  gat_edge2<<<gE2, 256, 0, stream>>>(hh, sab, dab, rowp, colb, b1, g1, be1, lnbuf, N);

  // ---- Layer 2: 64 -> (2x32) + LN + ReLU ----
  gat_gemm3<64, 64, 2, false><<<gG12, 256, 0, stream>>>(lnbuf, W2, as2, ad2, hh, sab, dab, N);
  gat_edge2<<<gE2, 256, 0, stream>>>(hh, sab, dab, rowp, colb, b2, g2, be2, lnbuf, N);

  // ---- Layer 3: 64 -> (1x32), no LN ----
  gat_gemm3<64, 32, 1, false><<<gG3, 256, 0, stream>>>(lnbuf, W3, as3, ad3, hh, sab, dab, N);
  gat_edge1<<<gE1, 256, 0, stream>>>(hh, sab, dab, rowp, colb, b3, (float*)d_out, N);
}

// Round 12
// 220.204 us; speedup vs baseline: 1.3862x; 1.3862x over previous
//
#include <hip/hip_runtime.h>
#include <hip/hip_fp16.h>

#define LEAKY 0.2f
#define BSH 7
#define BN 128      // nodes per bucket = 1<<BSH
#define CHUNK 4096  // edges per partition workgroup
#define NBMAX 1024  // max buckets supported by LDS arrays

__device__ __forceinline__ float leaky(float l) {
  return l >= 0.f ? l : LEAKY * l;
}

typedef _Float16 f16x2 __attribute__((ext_vector_type(2)));

__device__ __forceinline__ float fdot2(unsigned a, unsigned b, float c) {
#if __has_builtin(__builtin_amdgcn_fdot2)
  return __builtin_amdgcn_fdot2(__builtin_bit_cast(f16x2, a),
                                __builtin_bit_cast(f16x2, b), c, false);
#else
  __half2 ha = *(__half2*)&a, hb = *(__half2*)&b;
  float2 fa = __half22float2(ha), fb = __half22float2(hb);
  return fmaf(fa.x, fb.x, fmaf(fa.y, fb.y, c));
#endif
}

__device__ __forceinline__ int packsplat(float w) {
  const __half2 s = __half2half2(__float2half(w));
  return *(const int*)&s;
}
__device__ __forceinline__ __half2 asH2(unsigned u) { return *(__half2*)&u; }

// ---------------- Tiled GEMM (fp16 LDS operands, dot2 inner, fp16-only output) ----------------
template<int K, int CO, int H, bool IN_F32>
__global__ __launch_bounds__(256, 6)
void gat_gemm3(const void* __restrict__ xin, const float* __restrict__ W,
               const float* __restrict__ atts, const float* __restrict__ attd,
               __half* __restrict__ hh, float* __restrict__ sa, float* __restrict__ da,
               int N) {
  constexpr int CG = CO / 4;          // 16 or 8
  constexpr int BM = (256 / CG) * 4;  // 64 or 128
  constexpr int BK = 64;
  constexpr int NK = K / BK;
  constexpr int C = CO / H;
  constexpr int LDW = BK / 2 + 4;

  __shared__ unsigned xs[BM][LDW];
  __shared__ unsigned ws[CO][LDW];

  const int t = (int)threadIdx.x;
  const int cg = t % CG;
  const int ng = t / CG;
  const int n0 = (int)blockIdx.x * BM;

  float acc[4][4] = {};

  for (int kb = 0; kb < NK; ++kb) {
    __syncthreads();
    if constexpr (IN_F32) {
      const float* x = (const float*)xin;
      constexpr int F4R = BK / 4;
      constexpr int TOT = BM * F4R;
      for (int f = t; f < TOT; f += 256) {
        const int r = f / F4R, c = f % F4R;
        int row = n0 + r; row = row < N ? row : N - 1;
        const float4 v = *(const float4*)(x + (size_t)row * K + kb * BK + c * 4);
        const __half2 h0 = __floats2half2_rn(v.x, v.y);
        const __half2 h1 = __floats2half2_rn(v.z, v.w);
        xs[r][c * 2]     = *(const unsigned*)&h0;
        xs[r][c * 2 + 1] = *(const unsigned*)&h1;
      }
    } else {
      const __half* x = (const __half*)xin;
      constexpr int U4R = BK / 8;
      constexpr int TOT = BM * U4R;
      for (int f = t; f < TOT; f += 256) {
        const int r = f / U4R, c = f % U4R;
        int row = n0 + r; row = row < N ? row : N - 1;
        const uint4 v = *(const uint4*)(x + (size_t)row * K + kb * BK + c * 8);
        *(uint4*)&xs[r][c * 4] = v;
      }
    }
    {
      constexpr int F4R = BK / 4;
      constexpr int TOT = CO * F4R;
      for (int f = t; f < TOT; f += 256) {
        const int r = f / F4R, c = f % F4R;
        const float4 v = *(const float4*)(W + (size_t)r * K + kb * BK + c * 4);
        const __half2 h0 = __floats2half2_rn(v.x, v.y);
        const __half2 h1 = __floats2half2_rn(v.z, v.w);
        ws[r][c * 2]     = *(const unsigned*)&h0;
        ws[r][c * 2 + 1] = *(const unsigned*)&h1;
      }
    }
    __syncthreads();
    #pragma unroll
    for (int k = 0; k < BK; k += 8) {
      uint4 xa[4], wb[4];
      #pragma unroll
      for (int i = 0; i < 4; ++i) xa[i] = *(const uint4*)&xs[ng * 4 + i][k / 2];
      #pragma unroll
      for (int j = 0; j < 4; ++j) wb[j] = *(const uint4*)&ws[cg + CG * j][k / 2];
      #pragma unroll
      for (int i = 0; i < 4; ++i) {
        #pragma unroll
        for (int j = 0; j < 4; ++j) {
          acc[i][j] = fdot2(xa[i].x, wb[j].x, acc[i][j]);
          acc[i][j] = fdot2(xa[i].y, wb[j].y, acc[i][j]);
          acc[i][j] = fdot2(xa[i].z, wb[j].z, acc[i][j]);
          acc[i][j] = fdot2(xa[i].w, wb[j].w, acc[i][j]);
        }
      }
    }
  }

  float as_[4], ad_[4];
  #pragma unroll
  for (int j = 0; j < 4; ++j) {
    as_[j] = atts[cg + CG * j];
    ad_[j] = attd[cg + CG * j];
  }
  float ps[4][H] = {}, pd[4][H] = {};
  #pragma unroll
  for (int i = 0; i < 4; ++i) {
    #pragma unroll
    for (int j = 0; j < 4; ++j) {
      const int hd = (CG * j) / C;
      ps[i][hd] = fmaf(acc[i][j], as_[j], ps[i][hd]);
      pd[i][hd] = fmaf(acc[i][j], ad_[j], pd[i][hd]);
    }
  }
  #pragma unroll
  for (int m = 1; m < CG; m <<= 1) {
    #pragma unroll
    for (int i = 0; i < 4; ++i) {
      #pragma unroll
      for (int hd = 0; hd < H; ++hd) {
        ps[i][hd] += __shfl_xor(ps[i][hd], m, 64);
        pd[i][hd] += __shfl_xor(pd[i][hd], m, 64);
      }
    }
  }

  #pragma unroll
  for (int i = 0; i < 4; ++i) {
    const int n = n0 + ng * 4 + i;
    if (n < N) {
      #pragma unroll
      for (int j = 0; j < 4; ++j)
        hh[(size_t)n * CO + cg + CG * j] = __float2half(acc[i][j]);
      if (cg == 0) {
        #pragma unroll
        for (int hd = 0; hd < H; ++hd) {
          sa[n * H + hd] = ps[i][hd];
          da[n * H + hd] = pd[i][hd];
        }
      }
    }
  }
}

// ---------------- Edge aggregation, H=2 (64 ch): 4 nodes/wave, pipelined ----------------
__global__ __launch_bounds__(256)
void gat_edge2(const __half* __restrict__ hh,
               const float* __restrict__ sa, const float* __restrict__ da,
               const int* __restrict__ rowp, const int* __restrict__ col,
               const float* __restrict__ bias, const float* __restrict__ gamma,
               const float* __restrict__ beta, __half* __restrict__ out, int N) {
  __shared__ int2 wst[4][4][17][2];   // [wave][quarter][edge(16)+pad][head]
  const int t = (int)threadIdx.x;
  const int lane = t & 63;
  const int wib = t >> 6;
  const int quarter = lane >> 4;
  const int l = lane & 15;            // channels 4l .. 4l+3
  const int headq = l >> 3;
  const int wgl = (int)((blockIdx.x * blockDim.x + t) >> 6);
  const int n = wgl * 4 + quarter;
  const bool valid = (n < N);
  const int nc = valid ? n : N - 1;
  const int beg = rowp[nc];
  const int end = rowp[nc + 1];
  const float2 dvv = *(const float2*)(da + (size_t)nc * 2);
  const __half2* __restrict__ hhp = (const __half2*)hh;

  const __half2 z = __float2half2_rn(0.f);
  __half2 aL0 = z, aH0 = z, aL1 = z, aH1 = z, aL2 = z, aH2 = z, aL3 = z, aH3 = z;
  __half2 q0 = z, q1 = z;

  // prefetch block 0
  int sP = 0; float2 pP = make_float2(0.f, 0.f);
  if (beg < end) {
    const int cnt0 = min(16, end - beg);
    if (l < cnt0) {
      sP = col[beg + l];
      pP = *(const float2*)(sa + (size_t)sP * 2);
    }
  }

  for (int b0 = beg; b0 < end; b0 += 16) {
    const int cnt = min(16, end - b0);
    if (l < cnt) {
      int2 e0; e0.x = sP; e0.y = packsplat(__expf(leaky(pP.x + dvv.x)));
      int2 e1; e1.x = sP; e1.y = packsplat(__expf(leaky(pP.y + dvv.y)));
      wst[wib][quarter][l][0] = e0;
      wst[wib][quarter][l][1] = e1;
    }
    const int nb0 = b0 + 16;
    if (nb0 < end) {
      const int ncnt = min(16, end - nb0);
      if (l < ncnt) {
        sP = col[nb0 + l];
        pP = *(const float2*)(sa + (size_t)sP * 2);
      }
    }
    int i = 0;
    for (; i + 8 <= cnt; i += 8) {
      int2 e[8];
      #pragma unroll
      for (int j = 0; j < 8; ++j) e[j] = wst[wib][quarter][i + j][headq];
      uint2 hv[8];
      #pragma unroll
      for (int j = 0; j < 8; ++j) hv[j] = *(const uint2*)(hhp + ((size_t)e[j].x << 5) + 2 * l);
      __half2 w[8];
      #pragma unroll
      for (int j = 0; j < 8; ++j) w[j] = asH2(e[j].y);
      q0 = __hadd2(q0, __hadd2(__hadd2(w[0], w[1]), __hadd2(w[2], w[3])));
      q1 = __hadd2(q1, __hadd2(__hadd2(w[4], w[5]), __hadd2(w[6], w[7])));
      aL0 = __hfma2(w[0], asH2(hv[0].x), aL0); aH0 = __hfma2(w[0], asH2(hv[0].y), aH0);
      aL1 = __hfma2(w[1], asH2(hv[1].x), aL1); aH1 = __hfma2(w[1], asH2(hv[1].y), aH1);
      aL2 = __hfma2(w[2], asH2(hv[2].x), aL2); aH2 = __hfma2(w[2], asH2(hv[2].y), aH2);
      aL3 = __hfma2(w[3], asH2(hv[3].x), aL3); aH3 = __hfma2(w[3], asH2(hv[3].y), aH3);
      aL0 = __hfma2(w[4], asH2(hv[4].x), aL0); aH0 = __hfma2(w[4], asH2(hv[4].y), aH0);
      aL1 = __hfma2(w[5], asH2(hv[5].x), aL1); aH1 = __hfma2(w[5], asH2(hv[5].y), aH1);
      aL2 = __hfma2(w[6], asH2(hv[6].x), aL2); aH2 = __hfma2(w[6], asH2(hv[6].y), aH2);
      aL3 = __hfma2(w[7], asH2(hv[7].x), aL3); aH3 = __hfma2(w[7], asH2(hv[7].y), aH3);
    }
    for (; i + 4 <= cnt; i += 4) {
      int2 e[4];
      #pragma unroll
      for (int j = 0; j < 4; ++j) e[j] = wst[wib][quarter][i + j][headq];
      uint2 hv[4];
      #pragma unroll
      for (int j = 0; j < 4; ++j) hv[j] = *(const uint2*)(hhp + ((size_t)e[j].x << 5) + 2 * l);
      __half2 w[4];
      #pragma unroll
      for (int j = 0; j < 4; ++j) w[j] = asH2(e[j].y);
      q0 = __hadd2(q0, __hadd2(__hadd2(w[0], w[1]), __hadd2(w[2], w[3])));
      aL0 = __hfma2(w[0], asH2(hv[0].x), aL0); aH0 = __hfma2(w[0], asH2(hv[0].y), aH0);
      aL1 = __hfma2(w[1], asH2(hv[1].x), aL1); aH1 = __hfma2(w[1], asH2(hv[1].y), aH1);
      aL2 = __hfma2(w[2], asH2(hv[2].x), aL2); aH2 = __hfma2(w[2], asH2(hv[2].y), aH2);
      aL3 = __hfma2(w[3], asH2(hv[3].x), aL3); aH3 = __hfma2(w[3], asH2(hv[3].y), aH3);
    }
    for (; i < cnt; ++i) {
      const int2 e = wst[wib][quarter][i][headq];
      const uint2 hv = *(const uint2*)(hhp + ((size_t)e.x << 5) + 2 * l);
      const __half2 w = asH2(e.y);
      q0 = __hadd2(q0, w);
      aL0 = __hfma2(w, asH2(hv.x), aL0);
      aH0 = __hfma2(w, asH2(hv.y), aH0);
    }
  }

  const float c0 = (__low2float(aL0) + __low2float(aL1)) + (__low2float(aL2) + __low2float(aL3));
  const float c1 = (__high2float(aL0) + __high2float(aL1)) + (__high2float(aL2) + __high2float(aL3));
  const float c2 = (__low2float(aH0) + __low2float(aH1)) + (__low2float(aH2) + __low2float(aH3));
  const float c3 = (__high2float(aH0) + __high2float(aH1)) + (__high2float(aH2) + __high2float(aH3));
  const float qf = __low2float(q0) + __low2float(q1);

  const float inv = 1.f / fmaxf(qf, 1e-16f);
  const uint2 hr = *(const uint2*)(hhp + ((size_t)nc << 5) + 2 * l);
  const float2 r01 = __half22float2(asH2(hr.x));
  const float2 r23 = __half22float2(asH2(hr.y));
  const float4 bi = *(const float4*)(bias + 4 * l);
  float v0 = c0 * inv + r01.x + bi.x;
  float v1 = c1 * inv + r01.y + bi.y;
  float v2 = c2 * inv + r23.x + bi.z;
  float v3 = c3 * inv + r23.y + bi.w;
  {
    float s = (v0 + v1) + (v2 + v3);
    #pragma unroll
    for (int m = 1; m < 16; m <<= 1) s += __shfl_xor(s, m, 64);
    const float mu = s * (1.f / 64.f);
    const float d0 = v0 - mu, d1 = v1 - mu, d2 = v2 - mu, d3 = v3 - mu;
    float vs = (d0 * d0 + d1 * d1) + (d2 * d2 + d3 * d3);
    #pragma unroll
    for (int m = 1; m < 16; m <<= 1) vs += __shfl_xor(vs, m, 64);
    const float rs = rsqrtf(vs * (1.f / 64.f) + 1e-5f);
    const float4 g = *(const float4*)(gamma + 4 * l);
    const float4 be = *(const float4*)(beta + 4 * l);
    v0 = fmaxf(d0 * rs * g.x + be.x, 0.f);
    v1 = fmaxf(d1 * rs * g.y + be.y, 0.f);
    v2 = fmaxf(d2 * rs * g.z + be.z, 0.f);
    v3 = fmaxf(d3 * rs * g.w + be.w, 0.f);
  }
  if (valid) {
    const __half2 o01 = __floats2half2_rn(v0, v1);
    const __half2 o23 = __floats2half2_rn(v2, v3);
    uint2 o; o.x = *(const unsigned*)&o01; o.y = *(const unsigned*)&o23;
    *(uint2*)(out + (size_t)n * 64 + 4 * l) = o;
  }
}

// ---------------- Edge aggregation, H=1 (32 ch): 8 nodes/wave, pipelined ----------------
__global__ __launch_bounds__(256)
void gat_edge1(const __half* __restrict__ hh,
               const float* __restrict__ sa, const float* __restrict__ da,
               const int* __restrict__ rowp, const int* __restrict__ col,
               const float* __restrict__ bias, float* __restrict__ out, int N) {
  __shared__ int2 wst[4][8][9];       // [wave][octet][edge(8)+pad]
  const int t = (int)threadIdx.x;
  const int lane = t & 63;
  const int wib = t >> 6;
  const int oct = lane >> 3;
  const int l = lane & 7;             // channels 4l .. 4l+3
  const int wgl = (int)((blockIdx.x * blockDim.x + t) >> 6);
  const int n = wgl * 8 + oct;
  const bool valid = (n < N);
  const int nc = valid ? n : N - 1;
  const int beg = rowp[nc];
  const int end = rowp[nc + 1];
  const float dv = da[nc];
  const __half2* __restrict__ hhp = (const __half2*)hh;

  const __half2 z = __float2half2_rn(0.f);
  __half2 aL0 = z, aH0 = z, aL1 = z, aH1 = z, aL2 = z, aH2 = z, aL3 = z, aH3 = z;
  __half2 q0 = z, q1 = z;

  int sP = 0; float pP = 0.f;
  if (beg < end) {
    const int cnt0 = min(8, end - beg);
    if (l < cnt0) { sP = col[beg + l]; pP = sa[sP]; }
  }

  for (int b0 = beg; b0 < end; b0 += 8) {
    const int cnt = min(8, end - b0);
    if (l < cnt) {
      int2 e; e.x = sP; e.y = packsplat(__expf(leaky(pP + dv)));
      wst[wib][oct][l] = e;
    }
    const int nb0 = b0 + 8;
    if (nb0 < end) {
      const int ncnt = min(8, end - nb0);
      if (l < ncnt) { sP = col[nb0 + l]; pP = sa[sP]; }
    }
    int i = 0;
    for (; i + 8 <= cnt; i += 8) {
      int2 e[8];
      #pragma unroll
      for (int j = 0; j < 8; ++j) e[j] = wst[wib][oct][i + j];
      uint2 hv[8];
      #pragma unroll
      for (int j = 0; j < 8; ++j) hv[j] = *(const uint2*)(hhp + ((size_t)e[j].x << 4) + 2 * l);
      __half2 w[8];
      #pragma unroll
      for (int j = 0; j < 8; ++j) w[j] = asH2(e[j].y);
      q0 = __hadd2(q0, __hadd2(__hadd2(w[0], w[1]), __hadd2(w[2], w[3])));
      q1 = __hadd2(q1, __hadd2(__hadd2(w[4], w[5]), __hadd2(w[6], w[7])));
      aL0 = __hfma2(w[0], asH2(hv[0].x), aL0); aH0 = __hfma2(w[0], asH2(hv[0].y), aH0);
      aL1 = __hfma2(w[1], asH2(hv[1].x), aL1); aH1 = __hfma2(w[1], asH2(hv[1].y), aH1);
      aL2 = __hfma2(w[2], asH2(hv[2].x), aL2); aH2 = __hfma2(w[2], asH2(hv[2].y), aH2);
      aL3 = __hfma2(w[3], asH2(hv[3].x), aL3); aH3 = __hfma2(w[3], asH2(hv[3].y), aH3);
      aL0 = __hfma2(w[4], asH2(hv[4].x), aL0); aH0 = __hfma2(w[4], asH2(hv[4].y), aH0);
      aL1 = __hfma2(w[5], asH2(hv[5].x), aL1); aH1 = __hfma2(w[5], asH2(hv[5].y), aH1);
      aL2 = __hfma2(w[6], asH2(hv[6].x), aL2); aH2 = __hfma2(w[6], asH2(hv[6].y), aH2);
      aL3 = __hfma2(w[7], asH2(hv[7].x), aL3); aH3 = __hfma2(w[7], asH2(hv[7].y), aH3);
    }
    for (; i + 4 <= cnt; i += 4) {
      int2 e[4];
      #pragma unroll
      for (int j = 0; j < 4; ++j) e[j] = wst[wib][oct][i + j];
      uint2 hv[4];
      #pragma unroll
      for (int j = 0; j < 4; ++j) hv[j] = *(const uint2*)(hhp + ((size_t)e[j].x << 4) + 2 * l);
      __half2 w[4];
      #pragma unroll
      for (int j = 0; j < 4; ++j) w[j] = asH2(e[j].y);
      q0 = __hadd2(q0, __hadd2(__hadd2(w[0], w[1]), __hadd2(w[2], w[3])));
      aL0 = __hfma2(w[0], asH2(hv[0].x), aL0); aH0 = __hfma2(w[0], asH2(hv[0].y), aH0);
      aL1 = __hfma2(w[1], asH2(hv[1].x), aL1); aH1 = __hfma2(w[1], asH2(hv[1].y), aH1);
      aL2 = __hfma2(w[2], asH2(hv[2].x), aL2); aH2 = __hfma2(w[2], asH2(hv[2].y), aH2);
      aL3 = __hfma2(w[3], asH2(hv[3].x), aL3); aH3 = __hfma2(w[3], asH2(hv[3].y), aH3);
    }
    for (; i < cnt; ++i) {
      const int2 e = wst[wib][oct][i];
      const uint2 hv = *(const uint2*)(hhp + ((size_t)e.x << 4) + 2 * l);
      const __half2 w = asH2(e.y);
      q0 = __hadd2(q0, w);
      aL0 = __hfma2(w, asH2(hv.x), aL0);
      aH0 = __hfma2(w, asH2(hv.y), aH0);
    }
  }

  const float c0 = (__low2float(aL0) + __low2float(aL1)) + (__low2float(aL2) + __low2float(aL3));
  const float c1 = (__high2float(aL0) + __high2float(aL1)) + (__high2float(aL2) + __high2float(aL3));
  const float c2 = (__low2float(aH0) + __low2float(aH1)) + (__low2float(aH2) + __low2float(aH3));
  const float c3 = (__high2float(aH0) + __high2float(aH1)) + (__high2float(aH2) + __high2float(aH3));
  const float qf = __low2float(q0) + __low2float(q1);

  if (valid) {
    const float inv = 1.f / fmaxf(qf, 1e-16f);
    const uint2 hr = *(const uint2*)(hhp + ((size_t)nc << 4) + 2 * l);
    const float2 r01 = __half22float2(asH2(hr.x));
    const float2 r23 = __half22float2(asH2(hr.y));
    const float4 bi = *(const float4*)(bias + 4 * l);
    float4 o;
    o.x = c0 * inv + r01.x + bi.x;
    o.y = c1 * inv + r01.y + bi.y;
    o.z = c2 * inv + r23.x + bi.z;
    o.w = c3 * inv + r23.y + bi.w;
    *(float4*)(out + (size_t)n * 32 + 4 * l) = o;
  }
}

// ---------------- CSR build: atomic-free radix partition (bucket-major cntmat) ----------------
// cntmat layout: [bucket][chunk] so each bucket's chunk-counts are contiguous.
// k_colscan: one block per bucket, parallel LDS exclusive scan. Zero global atomics.

__global__ __launch_bounds__(256)
void k_hist_chunk(const int* __restrict__ dst, int* __restrict__ cntmat,
                  int E, int NB, int NW) {
  __shared__ int lh[NBMAX];
  const int t = (int)threadIdx.x;
  const int chunk = (int)blockIdx.x;
  const int c0 = chunk * CHUNK;
  const int cnt = min(CHUNK, E - c0);
  for (int b = t; b < NB; b += 256) lh[b] = 0;
  __syncthreads();
  for (int i = t; i < cnt; i += 256)
    atomicAdd(&lh[dst[c0 + i] >> BSH], 1);
  __syncthreads();
  for (int b = t; b < NB; b += 256)
    cntmat[(size_t)b * NW + chunk] = lh[b];
}

// one block per bucket: exclusive scan of its NW chunk-counts (contiguous).
template<int VPT>
__global__ __launch_bounds__(256)
void k_colscan(int* __restrict__ cntmat, int* __restrict__ bcnt, int NW) {
  __shared__ int sm[256];
  const int b = (int)blockIdx.x;
  int* row = cntmat + (size_t)b * NW;
  const int t = (int)threadIdx.x;
  int v[VPT];
  int run = 0;
  #pragma unroll
  for (int j = 0; j < VPT; ++j) {
    const int c = t * VPT + j;
    v[j] = (c < NW) ? row[c] : 0;
    run += v[j];
  }
  sm[t] = run;
  __syncthreads();
  #pragma unroll
  for (int off = 1; off < 256; off <<= 1) {
    int xv = (t >= off) ? sm[t - off] : 0;
    __syncthreads();
    sm[t] += xv;
    __syncthreads();
  }
  int excl = sm[t] - run;
  #pragma unroll
  for (int j = 0; j < VPT; ++j) {
    const int c = t * VPT + j;
    if (c < NW) row[c] = excl;
    excl += v[j];
  }
  if (t == 255) bcnt[b] = sm[255];
}

__global__ void k_bscan(const int* __restrict__ bcnt, int nb,
                        int* __restrict__ bstart, int* __restrict__ rowp_last, int E) {
  __shared__ int sm[256];
  const int t = (int)threadIdx.x;
  int v[4];
  #pragma unroll
  for (int j = 0; j < 4; ++j) { int i = t * 4 + j; v[j] = (i < nb) ? bcnt[i] : 0; }
  const int tot = v[0] + v[1] + v[2] + v[3];
  sm[t] = tot; __syncthreads();
  #pragma unroll
  for (int off = 1; off < 256; off <<= 1) {
    int xv = (t >= off) ? sm[t - off] : 0;
    __syncthreads();
    sm[t] += xv;
    __syncthreads();
  }
  int excl = sm[t] - tot;
  #pragma unroll
  for (int j = 0; j < 4; ++j) {
    int i = t * 4 + j;
    if (i < nb) { bstart[i] = excl; excl += v[j]; }
  }
  if (t == 0) { bstart[nb] = E; *rowp_last = E; }
}

__global__ __launch_bounds__(256)
void k_part(const int* __restrict__ src, const int* __restrict__ dst,
            const int* __restrict__ bstart, const int* __restrict__ cntmat,
            int* __restrict__ pairs, int E, int NB, int NW) {
  __shared__ int lh[NBMAX];     // hist, then local cursor
  __shared__ int lofs[NBMAX];   // exclusive local scan
  __shared__ int gofs[NBMAX];   // reserved global run base
  __shared__ int stg[CHUNK];
  __shared__ short stgb[CHUNK];
  __shared__ int bsum[256];
  const int t = (int)threadIdx.x;
  const int chunk = (int)blockIdx.x;
  const int c0 = chunk * CHUNK;
  const int cnt = min(CHUNK, E - c0);

  for (int b = t; b < NB; b += 256) lh[b] = 0;
  __syncthreads();
  for (int i = t; i < cnt; i += 256)
    atomicAdd(&lh[dst[c0 + i] >> BSH], 1);
  __syncthreads();

  int v[4]; int run = 0;
  #pragma unroll
  for (int j = 0; j < 4; ++j) {
    const int b = t * 4 + j;
    v[j] = (b < NB) ? lh[b] : 0;
    run += v[j];
  }
  bsum[t] = run;
  __syncthreads();
  #pragma unroll
  for (int off = 1; off < 256; off <<= 1) {
    int xv = (t >= off) ? bsum[t - off] : 0;
    __syncthreads();
    bsum[t] += xv;
    __syncthreads();
  }
  int base = bsum[t] - run;
  #pragma unroll
  for (int j = 0; j < 4; ++j) {
    const int b = t * 4 + j;
    if (b < NB) lofs[b] = base;
    base += v[j];
  }
  __syncthreads();

  // atomic-free reservation: precomputed exclusive offsets (bucket-major)
  for (int b = t; b < NB; b += 256) {
    gofs[b] = bstart[b] + cntmat[(size_t)b * NW + chunk];
    lh[b] = lofs[b];
  }
  __syncthreads();

  for (int i = t; i < cnt; i += 256) {
    const int d = dst[c0 + i];
    const int b = d >> BSH;
    const int p = atomicAdd(&lh[b], 1);   // LDS only
    stg[p] = (src[c0 + i] << BSH) | (d & (BN - 1));
    stgb[p] = (short)b;
  }
  __syncthreads();

  for (int i = t; i < cnt; i += 256) {
    const int b = (int)stgb[i];
    pairs[gofs[b] + (i - lofs[b])] = stg[i];
  }
}

__global__ __launch_bounds__(256)
void k_bucket_csr(const int* __restrict__ pairs, const int* __restrict__ bstart,
                  int* __restrict__ rowp, int* __restrict__ col, int N) {
  __shared__ int ldeg[BN];
  __shared__ int lofs[BN];
  const int b = (int)blockIdx.x;
  const int t = (int)threadIdx.x;
  const int base = b << BSH;
  const int nn = min(BN, N - base);
  const int s0 = bstart[b];
  const int s1 = bstart[b + 1];

  if (t < BN) ldeg[t] = 0;
  __syncthreads();
  for (int i = s0 + t; i < s1; i += 256)
    atomicAdd(&ldeg[pairs[i] & (BN - 1)], 1);
  __syncthreads();
  if (t < BN) lofs[t] = ldeg[t];
  __syncthreads();
  #pragma unroll
  for (int off = 1; off < BN; off <<= 1) {
    int v = (t < BN && t >= off) ? lofs[t - off] : 0;
    __syncthreads();
    if (t < BN) lofs[t] += v;
    __syncthreads();
  }
  if (t < BN) {
    const int ofs = s0 + lofs[t] - ldeg[t];
    if (t < nn) rowp[base + t] = ofs;
    ldeg[t] = ofs;
  }
  __syncthreads();
  for (int i = s0 + t; i < s1; i += 256) {
    const int pr = pairs[i];
    const int p = atomicAdd(&ldeg[pr & (BN - 1)], 1);
    col[p] = pr >> BSH;
  }
}

extern "C" void kernel_launch(void* const* d_in, const int* in_sizes, int n_in,
                              void* d_out, int out_size, void* d_ws, size_t ws_size,
                              hipStream_t stream) {
  const float* x   = (const float*)d_in[0];
  const int* esrc  = (const int*)d_in[1];
  const int* edst  = (const int*)d_in[2];
  const float* W1  = (const float*)d_in[3];
  const float* as1 = (const float*)d_in[4];
  const float* ad1 = (const float*)d_in[5];
  const float* b1  = (const float*)d_in[6];
  const float* W2  = (const float*)d_in[7];
  const float* as2 = (const float*)d_in[8];
  const float* ad2 = (const float*)d_in[9];
  const float* b2  = (const float*)d_in[10];
  const float* W3  = (const float*)d_in[11];
  const float* as3 = (const float*)d_in[12];
  const float* ad3 = (const float*)d_in[13];
  const float* b3  = (const float*)d_in[14];
  const float* g1  = (const float*)d_in[15];
  const float* be1 = (const float*)d_in[16];
  const float* g2  = (const float*)d_in[17];
  const float* be2 = (const float*)d_in[18];

  const int N = in_sizes[0] / 128;
  const int E = in_sizes[1];
  const int NB = (N + BN - 1) / BN;
  const int NW = (E + CHUNK - 1) / CHUNK;

  char* ws = (char*)d_ws;
  size_t off = 0;
  auto alloc = [&](size_t bytes) -> void* {
    void* p = ws + off;
    off = (off + bytes + 255) & ~(size_t)255;
    return p;
  };
  __half* lnbuf = (__half*)alloc((size_t)N * 64 * 2);
  __half* hh   = (__half*)alloc((size_t)N * 64 * 2);
  float* sab   = (float*)alloc((size_t)N * 2 * 4);
  float* dab   = (float*)alloc((size_t)N * 2 * 4);
  int* rowp    = (int*)alloc((size_t)(N + 1) * 4);
  int* colb    = (int*)alloc((size_t)E * 4);
  int* bcnt    = (int*)alloc((size_t)NB * 4);
  int* bstart  = (int*)alloc((size_t)(NB + 1) * 4);
  int* cntmat  = (int*)alloc((size_t)NB * NW * 4);
  // pairs buffer: reuse d_out (N*32 floats = 12.8MB >= E*4 = 6.4MB);
  // lifetime ends before the final layer writes d_out.
  int* pairs = (E <= out_size) ? (int*)d_out : (int*)alloc((size_t)E * 4);
  (void)ws_size; (void)n_in;

  // ---- CSR build (zero global atomics) ----
  k_hist_chunk<<<NW, 256, 0, stream>>>(edst, cntmat, E, NB, NW);
  if (NW <= 512)        k_colscan<2><<<NB, 256, 0, stream>>>(cntmat, bcnt, NW);
  else if (NW <= 1024)  k_colscan<4><<<NB, 256, 0, stream>>>(cntmat, bcnt, NW);
  else                  k_colscan<8><<<NB, 256, 0, stream>>>(cntmat, bcnt, NW);
  k_bscan<<<1, 256, 0, stream>>>(bcnt, NB, bstart, rowp + N, E);
  k_part<<<NW, 256, 0, stream>>>(esrc, edst, bstart, cntmat, pairs, E, NB, NW);
  k_bucket_csr<<<NB, 256, 0, stream>>>(pairs, bstart, rowp, colb, N);

  const int gG12 = (N + 63) / 64;    // BM=64
  const int gG3  = (N + 127) / 128;  // BM=128
  const int gE2 = (N + 15) / 16;     // 4 nodes/wave * 4 waves/block
  const int gE1 = (N + 31) / 32;     // 8 nodes/wave * 4 waves/block

  // ---- Layer 1: 128 -> (2x32) + LN + ReLU ----
  gat_gemm3<128, 64, 2, true><<<gG12, 256, 0, stream>>>(x, W1, as1, ad1, hh, sab, dab, N);
  gat_edge2<<<gE2, 256, 0, stream>>>(hh, sab, dab, rowp, colb, b1, g1, be1, lnbuf, N);

  // ---- Layer 2: 64 -> (2x32) + LN + ReLU ----
  gat_gemm3<64, 64, 2, false><<<gG12, 256, 0, stream>>>(lnbuf, W2, as2, ad2, hh, sab, dab, N);
  gat_edge2<<<gE2, 256, 0, stream>>>(hh, sab, dab, rowp, colb, b2, g2, be2, lnbuf, N);

  // ---- Layer 3: 64 -> (1x32), no LN ----
  gat_gemm3<64, 32, 1, false><<<gG3, 256, 0, stream>>>(lnbuf, W3, as3, ad3, hh, sab, dab, N);
  gat_edge1<<<gE1, 256, 0, stream>>>(hh, sab, dab, rowp, colb, b3, (float*)d_out, N);
}

// Round 13
// 216.129 us; speedup vs baseline: 1.4124x; 1.0189x over previous
//
#include <hip/hip_runtime.h>
#include <hip/hip_fp16.h>

#define LEAKY 0.2f
#define BSH 7
#define BN 128      // nodes per bucket = 1<<BSH
#define CHUNK 4096  // edges per partition workgroup
#define NBMAX 1024  // max buckets supported by LDS arrays

__device__ __forceinline__ float leaky(float l) {
  return l >= 0.f ? l : LEAKY * l;
}

typedef _Float16 f16x2 __attribute__((ext_vector_type(2)));

__device__ __forceinline__ float fdot2(unsigned a, unsigned b, float c) {
#if __has_builtin(__builtin_amdgcn_fdot2)
  return __builtin_amdgcn_fdot2(__builtin_bit_cast(f16x2, a),
                                __builtin_bit_cast(f16x2, b), c, false);
#else
  __half2 ha = *(__half2*)&a, hb = *(__half2*)&b;
  float2 fa = __half22float2(ha), fb = __half22float2(hb);
  return fmaf(fa.x, fb.x, fmaf(fa.y, fb.y, c));
#endif
}

__device__ __forceinline__ int packsplat(float w) {
  const __half2 s = __half2half2(__float2half(w));
  return *(const int*)&s;
}
__device__ __forceinline__ __half2 asH2(unsigned u) { return *(__half2*)&u; }

// ---------------- Tiled GEMM (fp16 LDS operands, dot2 inner, fp16-only output) ----------------
template<int K, int CO, int H, bool IN_F32>
__global__ __launch_bounds__(256, 6)
void gat_gemm3(const void* __restrict__ xin, const float* __restrict__ W,
               const float* __restrict__ atts, const float* __restrict__ attd,
               __half* __restrict__ hh, float* __restrict__ sa, float* __restrict__ da,
               int N) {
  constexpr int CG = CO / 4;          // 16 or 8
  constexpr int BM = (256 / CG) * 4;  // 64 or 128
  constexpr int BK = 64;
  constexpr int NK = K / BK;
  constexpr int C = CO / H;
  constexpr int LDW = BK / 2 + 4;

  __shared__ unsigned xs[BM][LDW];
  __shared__ unsigned ws[CO][LDW];

  const int t = (int)threadIdx.x;
  const int cg = t % CG;
  const int ng = t / CG;
  const int n0 = (int)blockIdx.x * BM;

  float acc[4][4] = {};

  for (int kb = 0; kb < NK; ++kb) {
    __syncthreads();
    if constexpr (IN_F32) {
      const float* x = (const float*)xin;
      constexpr int F4R = BK / 4;
      constexpr int TOT = BM * F4R;
      for (int f = t; f < TOT; f += 256) {
        const int r = f / F4R, c = f % F4R;
        int row = n0 + r; row = row < N ? row : N - 1;
        const float4 v = *(const float4*)(x + (size_t)row * K + kb * BK + c * 4);
        const __half2 h0 = __floats2half2_rn(v.x, v.y);
        const __half2 h1 = __floats2half2_rn(v.z, v.w);
        xs[r][c * 2]     = *(const unsigned*)&h0;
        xs[r][c * 2 + 1] = *(const unsigned*)&h1;
      }
    } else {
      const __half* x = (const __half*)xin;
      constexpr int U4R = BK / 8;
      constexpr int TOT = BM * U4R;
      for (int f = t; f < TOT; f += 256) {
        const int r = f / U4R, c = f % U4R;
        int row = n0 + r; row = row < N ? row : N - 1;
        const uint4 v = *(const uint4*)(x + (size_t)row * K + kb * BK + c * 8);
        *(uint4*)&xs[r][c * 4] = v;
      }
    }
    {
      constexpr int F4R = BK / 4;
      constexpr int TOT = CO * F4R;
      for (int f = t; f < TOT; f += 256) {
        const int r = f / F4R, c = f % F4R;
        const float4 v = *(const float4*)(W + (size_t)r * K + kb * BK + c * 4);
        const __half2 h0 = __floats2half2_rn(v.x, v.y);
        const __half2 h1 = __floats2half2_rn(v.z, v.w);
        ws[r][c * 2]     = *(const unsigned*)&h0;
        ws[r][c * 2 + 1] = *(const unsigned*)&h1;
      }
    }
    __syncthreads();
    #pragma unroll
    for (int k = 0; k < BK; k += 8) {
      uint4 xa[4], wb[4];
      #pragma unroll
      for (int i = 0; i < 4; ++i) xa[i] = *(const uint4*)&xs[ng * 4 + i][k / 2];
      #pragma unroll
      for (int j = 0; j < 4; ++j) wb[j] = *(const uint4*)&ws[cg + CG * j][k / 2];
      #pragma unroll
      for (int i = 0; i < 4; ++i) {
        #pragma unroll
        for (int j = 0; j < 4; ++j) {
          acc[i][j] = fdot2(xa[i].x, wb[j].x, acc[i][j]);
          acc[i][j] = fdot2(xa[i].y, wb[j].y, acc[i][j]);
          acc[i][j] = fdot2(xa[i].z, wb[j].z, acc[i][j]);
          acc[i][j] = fdot2(xa[i].w, wb[j].w, acc[i][j]);
        }
      }
    }
  }

  float as_[4], ad_[4];
  #pragma unroll
  for (int j = 0; j < 4; ++j) {
    as_[j] = atts[cg + CG * j];
    ad_[j] = attd[cg + CG * j];
  }
  float ps[4][H] = {}, pd[4][H] = {};
  #pragma unroll
  for (int i = 0; i < 4; ++i) {
    #pragma unroll
    for (int j = 0; j < 4; ++j) {
      const int hd = (CG * j) / C;
      ps[i][hd] = fmaf(acc[i][j], as_[j], ps[i][hd]);
      pd[i][hd] = fmaf(acc[i][j], ad_[j], pd[i][hd]);
    }
  }
  #pragma unroll
  for (int m = 1; m < CG; m <<= 1) {
    #pragma unroll
    for (int i = 0; i < 4; ++i) {
      #pragma unroll
      for (int hd = 0; hd < H; ++hd) {
        ps[i][hd] += __shfl_xor(ps[i][hd], m, 64);
        pd[i][hd] += __shfl_xor(pd[i][hd], m, 64);
      }
    }
  }

  #pragma unroll
  for (int i = 0; i < 4; ++i) {
    const int n = n0 + ng * 4 + i;
    if (n < N) {
      #pragma unroll
      for (int j = 0; j < 4; ++j)
        hh[(size_t)n * CO + cg + CG * j] = __float2half(acc[i][j]);
      if (cg == 0) {
        #pragma unroll
        for (int hd = 0; hd < H; ++hd) {
          sa[n * H + hd] = ps[i][hd];
          da[n * H + hd] = pd[i][hd];
        }
      }
    }
  }
}

// ---------------- Edge aggregation, H=2 (64 ch): 8 nodes/wave, 16B/lane ----------------
// Lane owns 8 channels (uint4). 8-lane octet per node: one VMEM instr = 8 edge rows (1KB).
__global__ __launch_bounds__(256)
void gat_edge2(const __half* __restrict__ hh,
               const float* __restrict__ sa, const float* __restrict__ da,
               const int* __restrict__ rowp, const int* __restrict__ col,
               const float* __restrict__ bias, const float* __restrict__ gamma,
               const float* __restrict__ beta, __half* __restrict__ out, int N) {
  __shared__ int2 wst[4][8][9][2];    // [wave][oct][edge(8)+pad][head]
  const int t = (int)threadIdx.x;
  const int lane = t & 63;
  const int wib = t >> 6;
  const int oct = lane >> 3;
  const int l = lane & 7;             // channels 8l .. 8l+7
  const int headq = l >> 2;
  const int wgl = (int)((blockIdx.x * blockDim.x + t) >> 6);
  const int n = wgl * 8 + oct;
  const bool valid = (n < N);
  const int nc = valid ? n : N - 1;
  const int beg = rowp[nc];
  const int end = rowp[nc + 1];
  const float2 dvv = *(const float2*)(da + (size_t)nc * 2);
  const __half* __restrict__ hp = hh;

  const __half2 z = __float2half2_rn(0.f);
  __half2 A0 = z, A1 = z, A2 = z, A3 = z;
  __half2 B0 = z, B1 = z, B2 = z, B3 = z;
  __half2 qA = z, qB = z;

  // prefetch block 0 (8 edges: lane l loads edge beg+l)
  int sP = 0; float2 pP = make_float2(0.f, 0.f);
  if (beg < end) {
    const int c0 = min(8, end - beg);
    if (l < c0) { sP = col[beg + l]; pP = *(const float2*)(sa + (size_t)sP * 2); }
  }

  for (int b0 = beg; b0 < end; b0 += 8) {
    const int cnt = min(8, end - b0);
    if (l < cnt) {
      int2 e0; e0.x = sP; e0.y = packsplat(__expf(leaky(pP.x + dvv.x)));
      int2 e1; e1.x = sP; e1.y = packsplat(__expf(leaky(pP.y + dvv.y)));
      wst[wib][oct][l][0] = e0;
      wst[wib][oct][l][1] = e1;
    }
    const int nb0 = b0 + 8;
    if (nb0 < end) {
      const int ncnt = min(8, end - nb0);
      if (l < ncnt) { sP = col[nb0 + l]; pP = *(const float2*)(sa + (size_t)sP * 2); }
    }
    int i = 0;
    for (; i + 4 <= cnt; i += 4) {
      const int2 e0 = wst[wib][oct][i][headq];
      const int2 e1 = wst[wib][oct][i + 1][headq];
      const int2 e2 = wst[wib][oct][i + 2][headq];
      const int2 e3 = wst[wib][oct][i + 3][headq];
      const uint4 h0 = *(const uint4*)(hp + ((size_t)e0.x << 6) + 8 * l);
      const uint4 h1 = *(const uint4*)(hp + ((size_t)e1.x << 6) + 8 * l);
      const uint4 h2 = *(const uint4*)(hp + ((size_t)e2.x << 6) + 8 * l);
      const uint4 h3 = *(const uint4*)(hp + ((size_t)e3.x << 6) + 8 * l);
      const __half2 w0 = asH2(e0.y), w1 = asH2(e1.y), w2 = asH2(e2.y), w3 = asH2(e3.y);
      qA = __hadd2(qA, __hadd2(w0, w1));
      qB = __hadd2(qB, __hadd2(w2, w3));
      A0 = __hfma2(w0, asH2(h0.x), A0); A1 = __hfma2(w0, asH2(h0.y), A1);
      A2 = __hfma2(w0, asH2(h0.z), A2); A3 = __hfma2(w0, asH2(h0.w), A3);
      B0 = __hfma2(w1, asH2(h1.x), B0); B1 = __hfma2(w1, asH2(h1.y), B1);
      B2 = __hfma2(w1, asH2(h1.z), B2); B3 = __hfma2(w1, asH2(h1.w), B3);
      A0 = __hfma2(w2, asH2(h2.x), A0); A1 = __hfma2(w2, asH2(h2.y), A1);
      A2 = __hfma2(w2, asH2(h2.z), A2); A3 = __hfma2(w2, asH2(h2.w), A3);
      B0 = __hfma2(w3, asH2(h3.x), B0); B1 = __hfma2(w3, asH2(h3.y), B1);
      B2 = __hfma2(w3, asH2(h3.z), B2); B3 = __hfma2(w3, asH2(h3.w), B3);
    }
    for (; i < cnt; ++i) {
      const int2 e = wst[wib][oct][i][headq];
      const uint4 hv = *(const uint4*)(hp + ((size_t)e.x << 6) + 8 * l);
      const __half2 w = asH2(e.y);
      qA = __hadd2(qA, w);
      A0 = __hfma2(w, asH2(hv.x), A0); A1 = __hfma2(w, asH2(hv.y), A1);
      A2 = __hfma2(w, asH2(hv.z), A2); A3 = __hfma2(w, asH2(hv.w), A3);
    }
  }

  const float c0 = __low2float(A0) + __low2float(B0);
  const float c1 = __high2float(A0) + __high2float(B0);
  const float c2 = __low2float(A1) + __low2float(B1);
  const float c3 = __high2float(A1) + __high2float(B1);
  const float c4 = __low2float(A2) + __low2float(B2);
  const float c5 = __high2float(A2) + __high2float(B2);
  const float c6 = __low2float(A3) + __low2float(B3);
  const float c7 = __high2float(A3) + __high2float(B3);
  const float qf = __low2float(qA) + __low2float(qB);

  const float inv = 1.f / fmaxf(qf, 1e-16f);
  const uint4 hr = *(const uint4*)(hp + ((size_t)nc << 6) + 8 * l);
  const float2 r0 = __half22float2(asH2(hr.x));
  const float2 r1 = __half22float2(asH2(hr.y));
  const float2 r2 = __half22float2(asH2(hr.z));
  const float2 r3 = __half22float2(asH2(hr.w));
  const float4 bi0 = *(const float4*)(bias + 8 * l);
  const float4 bi1 = *(const float4*)(bias + 8 * l + 4);
  float v0 = c0 * inv + r0.x + bi0.x;
  float v1 = c1 * inv + r0.y + bi0.y;
  float v2 = c2 * inv + r1.x + bi0.z;
  float v3 = c3 * inv + r1.y + bi0.w;
  float v4 = c4 * inv + r2.x + bi1.x;
  float v5 = c5 * inv + r2.y + bi1.y;
  float v6 = c6 * inv + r3.x + bi1.z;
  float v7 = c7 * inv + r3.y + bi1.w;
  {
    float s = ((v0 + v1) + (v2 + v3)) + ((v4 + v5) + (v6 + v7));
    s += __shfl_xor(s, 1, 64); s += __shfl_xor(s, 2, 64); s += __shfl_xor(s, 4, 64);
    const float mu = s * (1.f / 64.f);
    const float d0 = v0 - mu, d1 = v1 - mu, d2 = v2 - mu, d3 = v3 - mu;
    const float d4 = v4 - mu, d5 = v5 - mu, d6 = v6 - mu, d7 = v7 - mu;
    float vs = ((d0 * d0 + d1 * d1) + (d2 * d2 + d3 * d3)) +
               ((d4 * d4 + d5 * d5) + (d6 * d6 + d7 * d7));
    vs += __shfl_xor(vs, 1, 64); vs += __shfl_xor(vs, 2, 64); vs += __shfl_xor(vs, 4, 64);
    const float rs = rsqrtf(vs * (1.f / 64.f) + 1e-5f);
    const float4 g0 = *(const float4*)(gamma + 8 * l);
    const float4 g1 = *(const float4*)(gamma + 8 * l + 4);
    const float4 e0 = *(const float4*)(beta + 8 * l);
    const float4 e1 = *(const float4*)(beta + 8 * l + 4);
    v0 = fmaxf(d0 * rs * g0.x + e0.x, 0.f);
    v1 = fmaxf(d1 * rs * g0.y + e0.y, 0.f);
    v2 = fmaxf(d2 * rs * g0.z + e0.z, 0.f);
    v3 = fmaxf(d3 * rs * g0.w + e0.w, 0.f);
    v4 = fmaxf(d4 * rs * g1.x + e1.x, 0.f);
    v5 = fmaxf(d5 * rs * g1.y + e1.y, 0.f);
    v6 = fmaxf(d6 * rs * g1.z + e1.z, 0.f);
    v7 = fmaxf(d7 * rs * g1.w + e1.w, 0.f);
  }
  if (valid) {
    const __half2 o0 = __floats2half2_rn(v0, v1);
    const __half2 o1 = __floats2half2_rn(v2, v3);
    const __half2 o2 = __floats2half2_rn(v4, v5);
    const __half2 o3 = __floats2half2_rn(v6, v7);
    uint4 o;
    o.x = *(const unsigned*)&o0; o.y = *(const unsigned*)&o1;
    o.z = *(const unsigned*)&o2; o.w = *(const unsigned*)&o3;
    *(uint4*)(out + (size_t)n * 64 + 8 * l) = o;
  }
}

// ---------------- Edge aggregation, H=1 (32 ch): 16 nodes/wave, 16B/lane ----------------
__global__ __launch_bounds__(256)
void gat_edge1(const __half* __restrict__ hh,
               const float* __restrict__ sa, const float* __restrict__ da,
               const int* __restrict__ rowp, const int* __restrict__ col,
               const float* __restrict__ bias, float* __restrict__ out, int N) {
  __shared__ int2 wst[4][16][5];      // [wave][node(16)][edge(4)+pad]
  const int t = (int)threadIdx.x;
  const int lane = t & 63;
  const int wib = t >> 6;
  const int nq = lane >> 2;           // node within wave
  const int l = lane & 3;             // channels 8l .. 8l+7
  const int wgl = (int)((blockIdx.x * blockDim.x + t) >> 6);
  const int n = wgl * 16 + nq;
  const bool valid = (n < N);
  const int nc = valid ? n : N - 1;
  const int beg = rowp[nc];
  const int end = rowp[nc + 1];
  const float dv = da[nc];
  const __half* __restrict__ hp = hh;

  const __half2 z = __float2half2_rn(0.f);
  __half2 A0 = z, A1 = z, A2 = z, A3 = z;
  __half2 B0 = z, B1 = z, B2 = z, B3 = z;
  __half2 qA = z, qB = z;

  // prefetch block 0 (4 edges: lane l loads edge beg+l)
  int sP = 0; float pP = 0.f;
  if (beg < end) {
    const int c0 = min(4, end - beg);
    if (l < c0) { sP = col[beg + l]; pP = sa[sP]; }
  }

  for (int b0 = beg; b0 < end; b0 += 4) {
    const int cnt = min(4, end - b0);
    if (l < cnt) {
      int2 e; e.x = sP; e.y = packsplat(__expf(leaky(pP + dv)));
      wst[wib][nq][l] = e;
    }
    const int nb0 = b0 + 4;
    if (nb0 < end) {
      const int ncnt = min(4, end - nb0);
      if (l < ncnt) { sP = col[nb0 + l]; pP = sa[sP]; }
    }
    if (cnt == 4) {
      const int2 e0 = wst[wib][nq][0];
      const int2 e1 = wst[wib][nq][1];
      const int2 e2 = wst[wib][nq][2];
      const int2 e3 = wst[wib][nq][3];
      const uint4 h0 = *(const uint4*)(hp + ((size_t)e0.x << 5) + 8 * l);
      const uint4 h1 = *(const uint4*)(hp + ((size_t)e1.x << 5) + 8 * l);
      const uint4 h2 = *(const uint4*)(hp + ((size_t)e2.x << 5) + 8 * l);
      const uint4 h3 = *(const uint4*)(hp + ((size_t)e3.x << 5) + 8 * l);
      const __half2 w0 = asH2(e0.y), w1 = asH2(e1.y), w2 = asH2(e2.y), w3 = asH2(e3.y);
      qA = __hadd2(qA, __hadd2(w0, w1));
      qB = __hadd2(qB, __hadd2(w2, w3));
      A0 = __hfma2(w0, asH2(h0.x), A0); A1 = __hfma2(w0, asH2(h0.y), A1);
      A2 = __hfma2(w0, asH2(h0.z), A2); A3 = __hfma2(w0, asH2(h0.w), A3);
      B0 = __hfma2(w1, asH2(h1.x), B0); B1 = __hfma2(w1, asH2(h1.y), B1);
      B2 = __hfma2(w1, asH2(h1.z), B2); B3 = __hfma2(w1, asH2(h1.w), B3);
      A0 = __hfma2(w2, asH2(h2.x), A0); A1 = __hfma2(w2, asH2(h2.y), A1);
      A2 = __hfma2(w2, asH2(h2.z), A2); A3 = __hfma2(w2, asH2(h2.w), A3);
      B0 = __hfma2(w3, asH2(h3.x), B0); B1 = __hfma2(w3, asH2(h3.y), B1);
      B2 = __hfma2(w3, asH2(h3.z), B2); B3 = __hfma2(w3, asH2(h3.w), B3);
    } else {
      for (int i = 0; i < cnt; ++i) {
        const int2 e = wst[wib][nq][i];
        const uint4 hv = *(const uint4*)(hp + ((size_t)e.x << 5) + 8 * l);
        const __half2 w = asH2(e.y);
        qA = __hadd2(qA, w);
        A0 = __hfma2(w, asH2(hv.x), A0); A1 = __hfma2(w, asH2(hv.y), A1);
        A2 = __hfma2(w, asH2(hv.z), A2); A3 = __hfma2(w, asH2(hv.w), A3);
      }
    }
  }

  if (valid) {
    const float c0 = __low2float(A0) + __low2float(B0);
    const float c1 = __high2float(A0) + __high2float(B0);
    const float c2 = __low2float(A1) + __low2float(B1);
    const float c3 = __high2float(A1) + __high2float(B1);
    const float c4 = __low2float(A2) + __low2float(B2);
    const float c5 = __high2float(A2) + __high2float(B2);
    const float c6 = __low2float(A3) + __low2float(B3);
    const float c7 = __high2float(A3) + __high2float(B3);
    const float qf = __low2float(qA) + __low2float(qB);
    const float inv = 1.f / fmaxf(qf, 1e-16f);
    const uint4 hr = *(const uint4*)(hp + ((size_t)nc << 5) + 8 * l);
    const float2 r0 = __half22float2(asH2(hr.x));
    const float2 r1 = __half22float2(asH2(hr.y));
    const float2 r2 = __half22float2(asH2(hr.z));
    const float2 r3 = __half22float2(asH2(hr.w));
    const float4 bi0 = *(const float4*)(bias + 8 * l);
    const float4 bi1 = *(const float4*)(bias + 8 * l + 4);
    float4 oA, oB;
    oA.x = c0 * inv + r0.x + bi0.x;
    oA.y = c1 * inv + r0.y + bi0.y;
    oA.z = c2 * inv + r1.x + bi0.z;
    oA.w = c3 * inv + r1.y + bi0.w;
    oB.x = c4 * inv + r2.x + bi1.x;
    oB.y = c5 * inv + r2.y + bi1.y;
    oB.z = c6 * inv + r3.x + bi1.z;
    oB.w = c7 * inv + r3.y + bi1.w;
    *(float4*)(out + (size_t)n * 32 + 8 * l) = oA;
    *(float4*)(out + (size_t)n * 32 + 8 * l + 4) = oB;
  }
}

// ---------------- CSR build: atomic-free radix partition (bucket-major cntmat) ----------------
__global__ __launch_bounds__(256)
void k_hist_chunk(const int* __restrict__ dst, int* __restrict__ cntmat,
                  int E, int NB, int NW) {
  __shared__ int lh[NBMAX];
  const int t = (int)threadIdx.x;
  const int chunk = (int)blockIdx.x;
  const int c0 = chunk * CHUNK;
  const int cnt = min(CHUNK, E - c0);
  for (int b = t; b < NB; b += 256) lh[b] = 0;
  __syncthreads();
  for (int i = t; i < cnt; i += 256)
    atomicAdd(&lh[dst[c0 + i] >> BSH], 1);
  __syncthreads();
  for (int b = t; b < NB; b += 256)
    cntmat[(size_t)b * NW + chunk] = lh[b];
}

template<int VPT>
__global__ __launch_bounds__(256)
void k_colscan(int* __restrict__ cntmat, int* __restrict__ bcnt, int NW) {
  __shared__ int sm[256];
  const int b = (int)blockIdx.x;
  int* row = cntmat + (size_t)b * NW;
  const int t = (int)threadIdx.x;
  int v[VPT];
  int run = 0;
  #pragma unroll
  for (int j = 0; j < VPT; ++j) {
    const int c = t * VPT + j;
    v[j] = (c < NW) ? row[c] : 0;
    run += v[j];
  }
  sm[t] = run;
  __syncthreads();
  #pragma unroll
  for (int off = 1; off < 256; off <<= 1) {
    int xv = (t >= off) ? sm[t - off] : 0;
    __syncthreads();
    sm[t] += xv;
    __syncthreads();
  }
  int excl = sm[t] - run;
  #pragma unroll
  for (int j = 0; j < VPT; ++j) {
    const int c = t * VPT + j;
    if (c < NW) row[c] = excl;
    excl += v[j];
  }
  if (t == 255) bcnt[b] = sm[255];
}

__global__ void k_bscan(const int* __restrict__ bcnt, int nb,
                        int* __restrict__ bstart, int* __restrict__ rowp_last, int E) {
  __shared__ int sm[256];
  const int t = (int)threadIdx.x;
  int v[4];
  #pragma unroll
  for (int j = 0; j < 4; ++j) { int i = t * 4 + j; v[j] = (i < nb) ? bcnt[i] : 0; }
  const int tot = v[0] + v[1] + v[2] + v[3];
  sm[t] = tot; __syncthreads();
  #pragma unroll
  for (int off = 1; off < 256; off <<= 1) {
    int xv = (t >= off) ? sm[t - off] : 0;
    __syncthreads();
    sm[t] += xv;
    __syncthreads();
  }
  int excl = sm[t] - tot;
  #pragma unroll
  for (int j = 0; j < 4; ++j) {
    int i = t * 4 + j;
    if (i < nb) { bstart[i] = excl; excl += v[j]; }
  }
  if (t == 0) { bstart[nb] = E; *rowp_last = E; }
}

__global__ __launch_bounds__(256)
void k_part(const int* __restrict__ src, const int* __restrict__ dst,
            const int* __restrict__ bstart, const int* __restrict__ cntmat,
            int* __restrict__ pairs, int E, int NB, int NW) {
  __shared__ int lh[NBMAX];
  __shared__ int lofs[NBMAX];
  __shared__ int gofs[NBMAX];
  __shared__ int stg[CHUNK];
  __shared__ short stgb[CHUNK];
  __shared__ int bsum[256];
  const int t = (int)threadIdx.x;
  const int chunk = (int)blockIdx.x;
  const int c0 = chunk * CHUNK;
  const int cnt = min(CHUNK, E - c0);

  for (int b = t; b < NB; b += 256) lh[b] = 0;
  __syncthreads();
  for (int i = t; i < cnt; i += 256)
    atomicAdd(&lh[dst[c0 + i] >> BSH], 1);
  __syncthreads();

  int v[4]; int run = 0;
  #pragma unroll
  for (int j = 0; j < 4; ++j) {
    const int b = t * 4 + j;
    v[j] = (b < NB) ? lh[b] : 0;
    run += v[j];
  }
  bsum[t] = run;
  __syncthreads();
  #pragma unroll
  for (int off = 1; off < 256; off <<= 1) {
    int xv = (t >= off) ? bsum[t - off] : 0;
    __syncthreads();
    bsum[t] += xv;
    __syncthreads();
  }
  int base = bsum[t] - run;
  #pragma unroll
  for (int j = 0; j < 4; ++j) {
    const int b = t * 4 + j;
    if (b < NB) lofs[b] = base;
    base += v[j];
  }
  __syncthreads();

  for (int b = t; b < NB; b += 256) {
    gofs[b] = bstart[b] + cntmat[(size_t)b * NW + chunk];
    lh[b] = lofs[b];
  }
  __syncthreads();

  for (int i = t; i < cnt; i += 256) {
    const int d = dst[c0 + i];
    const int b = d >> BSH;
    const int p = atomicAdd(&lh[b], 1);   // LDS only
    stg[p] = (src[c0 + i] << BSH) | (d & (BN - 1));
    stgb[p] = (short)b;
  }
  __syncthreads();

  for (int i = t; i < cnt; i += 256) {
    const int b = (int)stgb[i];
    pairs[gofs[b] + (i - lofs[b])] = stg[i];
  }
}

__global__ __launch_bounds__(256)
void k_bucket_csr(const int* __restrict__ pairs, const int* __restrict__ bstart,
                  int* __restrict__ rowp, int* __restrict__ col, int N) {
  __shared__ int ldeg[BN];
  __shared__ int lofs[BN];
  const int b = (int)blockIdx.x;
  const int t = (int)threadIdx.x;
  const int base = b << BSH;
  const int nn = min(BN, N - base);
  const int s0 = bstart[b];
  const int s1 = bstart[b + 1];

  if (t < BN) ldeg[t] = 0;
  __syncthreads();
  for (int i = s0 + t; i < s1; i += 256)
    atomicAdd(&ldeg[pairs[i] & (BN - 1)], 1);
  __syncthreads();
  if (t < BN) lofs[t] = ldeg[t];
  __syncthreads();
  #pragma unroll
  for (int off = 1; off < BN; off <<= 1) {
    int v = (t < BN && t >= off) ? lofs[t - off] : 0;
    __syncthreads();
    if (t < BN) lofs[t] += v;
    __syncthreads();
  }
  if (t < BN) {
    const int ofs = s0 + lofs[t] - ldeg[t];
    if (t < nn) rowp[base + t] = ofs;
    ldeg[t] = ofs;
  }
  __syncthreads();
  for (int i = s0 + t; i < s1; i += 256) {
    const int pr = pairs[i];
    const int p = atomicAdd(&ldeg[pr & (BN - 1)], 1);
    col[p] = pr >> BSH;
  }
}

extern "C" void kernel_launch(void* const* d_in, const int* in_sizes, int n_in,
                              void* d_out, int out_size, void* d_ws, size_t ws_size,
                              hipStream_t stream) {
  const float* x   = (const float*)d_in[0];
  const int* esrc  = (const int*)d_in[1];
  const int* edst  = (const int*)d_in[2];
  const float* W1  = (const float*)d_in[3];
  const float* as1 = (const float*)d_in[4];
  const float* ad1 = (const float*)d_in[5];
  const float* b1  = (const float*)d_in[6];
  const float* W2  = (const float*)d_in[7];
  const float* as2 = (const float*)d_in[8];
  const float* ad2 = (const float*)d_in[9];
  const float* b2  = (const float*)d_in[10];
  const float* W3  = (const float*)d_in[11];
  const float* as3 = (const float*)d_in[12];
  const float* ad3 = (const float*)d_in[13];
  const float* b3  = (const float*)d_in[14];
  const float* g1  = (const float*)d_in[15];
  const float* be1 = (const float*)d_in[16];
  const float* g2  = (const float*)d_in[17];
  const float* be2 = (const float*)d_in[18];

  const int N = in_sizes[0] / 128;
  const int E = in_sizes[1];
  const int NB = (N + BN - 1) / BN;
  const int NW = (E + CHUNK - 1) / CHUNK;

  char* ws = (char*)d_ws;
  size_t off = 0;
  auto alloc = [&](size_t bytes) -> void* {
    void* p = ws + off;
    off = (off + bytes + 255) & ~(size_t)255;
    return p;
  };
  __half* lnbuf = (__half*)alloc((size_t)N * 64 * 2);
  __half* hh   = (__half*)alloc((size_t)N * 64 * 2);
  float* sab   = (float*)alloc((size_t)N * 2 * 4);
  float* dab   = (float*)alloc((size_t)N * 2 * 4);
  int* rowp    = (int*)alloc((size_t)(N + 1) * 4);
  int* colb    = (int*)alloc((size_t)E * 4);
  int* bcnt    = (int*)alloc((size_t)NB * 4);
  int* bstart  = (int*)alloc((size_t)(NB + 1) * 4);
  int* cntmat  = (int*)alloc((size_t)NB * NW * 4);
  // pairs buffer: reuse d_out (N*32 floats = 12.8MB >= E*4 = 6.4MB);
  // lifetime ends before the final layer writes d_out.
  int* pairs = (E <= out_size) ? (int*)d_out : (int*)alloc((size_t)E * 4);
  (void)ws_size; (void)n_in;

  // ---- CSR build (zero global atomics) ----
  k_hist_chunk<<<NW, 256, 0, stream>>>(edst, cntmat, E, NB, NW);
  if (NW <= 512)        k_colscan<2><<<NB, 256, 0, stream>>>(cntmat, bcnt, NW);
  else if (NW <= 1024)  k_colscan<4><<<NB, 256, 0, stream>>>(cntmat, bcnt, NW);
  else                  k_colscan<8><<<NB, 256, 0, stream>>>(cntmat, bcnt, NW);
  k_bscan<<<1, 256, 0, stream>>>(bcnt, NB, bstart, rowp + N, E);
  k_part<<<NW, 256, 0, stream>>>(esrc, edst, bstart, cntmat, pairs, E, NB, NW);
  k_bucket_csr<<<NB, 256, 0, stream>>>(pairs, bstart, rowp, colb, N);

  const int gG12 = (N + 63) / 64;    // BM=64
  const int gG3  = (N + 127) / 128;  // BM=128
  const int gE2 = (N + 31) / 32;     // 8 nodes/wave * 4 waves/block
  const int gE1 = (N + 63) / 64;     // 16 nodes/wave * 4 waves/block

  // ---- Layer 1: 128 -> (2x32) + LN + ReLU ----
  gat_gemm3<128, 64, 2, true><<<gG12, 256, 0, stream>>>(x, W1, as1, ad1, hh, sab, dab, N);
  gat_edge2<<<gE2, 256, 0, stream>>>(hh, sab, dab, rowp, colb, b1, g1, be1, lnbuf, N);

  // ---- Layer 2: 64 -> (2x32) + LN + ReLU ----
  gat_gemm3<64, 64, 2, false><<<gG12, 256, 0, stream>>>(lnbuf, W2, as2, ad2, hh, sab, dab, N);
  gat_edge2<<<gE2, 256, 0, stream>>>(hh, sab, dab, rowp, colb, b2, g2, be2, lnbuf, N);

  // ---- Layer 3: 64 -> (1x32), no LN ----
  gat_gemm3<64, 32, 1, false><<<gG3, 256, 0, stream>>>(lnbuf, W3, as3, ad3, hh, sab, dab, N);
  gat_edge1<<<gE1, 256, 0, stream>>>(hh, sab, dab, rowp, colb, b3, (float*)d_out, N);
}